// Round 11
// baseline (165.931 us; speedup 1.0000x reference)
//
#include <hip/hip_runtime.h>

// RRF2d: y[b,o,p] = sum_l patches[b,l,p] * W[o,l,p] + bias[o,p]
// B=32, C_IN=32, H=W=64, K=3 pad=1, C_OUT=64, L=4096, KL=288
//
// R11 = R10 (163us) + x staged through LDS DMA with c-ahead prefetch.
// Each wave's x region (8 b x 4 tap-rows x 64 cols = 8 KB) is PRIVATE, so
// it is single-buffered with no extra barriers: stage_x(c+1) issues right
// after the dh2 x ds_reads of c (behind an explicit lgkmcnt(0)), hiding
// under dh2 FMAs + the next top-of-loop convoy. The counted vmcnt(9) at
// loop top proves both w(c) and x(c) drained (x(c) older than w(c+1)'s 9).
// Compute body is pure LDS now (ds_read_b64 ~120cyc, compiler-pipelined):
// no global-latency chain per dh-stage. LDS 18 KB (w dbuf) + 32 KB (x) =
// 50 KB -> 3 blocks/CU. Block (64,4): 4 waves x 8 b = all 32 batches =>
// weights leave HBM exactly once. Grid 32 x 32 = 1024 blocks.

#define C_IN   32
#define H_SZ   64
#define W_SZ   64
#define C_OUT  64
#define L_SZ   4096
#define KL     288
#define XCH    (H_SZ * W_SZ)

__device__ __forceinline__ void gload_lds4(const float* g, float* l) {
    __builtin_amdgcn_global_load_lds(
        (const __attribute__((address_space(1))) void*)g,
        (__attribute__((address_space(3))) void*)l, 4, 0, 0);
}

// lane i <- lane i-1 (wave_shr:1). Lane 0 keeps own value (masked by caller).
__device__ __forceinline__ float dpp_shr1(float v) {
    int i = __builtin_bit_cast(int, v);
    int r = __builtin_amdgcn_update_dpp(i, i, 0x138, 0xF, 0xF, false);
    return __builtin_bit_cast(float, r);
}
// lane i <- lane i+1 (wave_shl:1). Lane 63 keeps own value (masked by caller).
__device__ __forceinline__ float dpp_shl1(float v) {
    int i = __builtin_bit_cast(int, v);
    int r = __builtin_amdgcn_update_dpp(i, i, 0x130, 0xF, 0xF, false);
    return __builtin_bit_cast(float, r);
}

__global__ __launch_bounds__(256, 3)
void rrf2d_kernel(const float* __restrict__ x,
                  const float* __restrict__ wgt,
                  const float* __restrict__ bias,
                  float* __restrict__ out) {
    __shared__ float wlds[2][9 * 2 * 128];   // 18 KB: [buf][(j*2+o)*128 + pl]
    __shared__ float xlds[32][4][64];        // 32 KB: [b][tap-row slot][col]

    const int t   = threadIdx.x;                                  // 0..63
    const int wyu = __builtin_amdgcn_readfirstlane(threadIdx.y);  // 0..3
    const int rb  = t >> 5;
    const int k   = t & 31;
    const int c0  = k * 2;
    const int h0  = blockIdx.x * 2;
    const int o0  = blockIdx.y * 2;
    const int b0  = wyu * 8;
    const int h   = h0 + rb;
    const int p   = h * W_SZ + c0;
    const int pl  = rb * 64 + c0;            // p_local (0..127)
    const int p0  = h0 * W_SZ;

    // block-uniform clamped SOURCE rows for the 4 x slots (h0-1 .. h0+2)
    int rowsrc[4];
    #pragma unroll
    for (int s = 0; s < 4; ++s) {
        int r = h0 - 1 + s;
        r = r < 0 ? 0 : (r > H_SZ - 1 ? H_SZ - 1 : r);
        rowsrc[s] = r * W_SZ;
    }
    // per-lane tap-row validity (row h+dh-1)
    float rvm[3];
    #pragma unroll
    for (int dh = 0; dh < 3; ++dh) {
        const int r = h + dh - 1;
        rvm[dh] = ((unsigned)r < (unsigned)H_SZ) ? 1.f : 0.f;
    }
    const bool lval = (k != 0), rval = (k != 31);

    float2 acc[8][2];
    #pragma unroll
    for (int i = 0; i < 8; ++i)
        #pragma unroll
        for (int j = 0; j < 2; ++j) { acc[i][j].x = 0.f; acc[i][j].y = 0.f; }

    const size_t obase[2] = { (size_t)o0 * (KL * (size_t)L_SZ) + p0,
                              (size_t)(o0 + 1) * (KL * (size_t)L_SZ) + p0 };

    // stage weights for channel cc into wlds[cc&1]: 9 DMA pieces per wave
    auto stage_w = [&](int cc) {
        float* dst = wlds[cc & 1];
        const size_t coff = (size_t)cc * 9 * L_SZ;
        #pragma unroll
        for (int s = 0; s < 9; ++s) {
            const int r = wyu * 9 + s;
            const int j = r >> 2, o = (r >> 1) & 1, q = r & 1;
            const float* g = wgt + obase[o] + coff + (size_t)j * L_SZ + q * 64 + t;
            gload_lds4(g, dst + (j * 2 + o) * 128 + q * 64);
        }
    };

    // stage this wave's x for channel cc: 8 b x 4 rows, 32 DMA pieces.
    // Region is PRIVATE to the wave (b0..b0+7) -> no barrier needed.
    auto stage_x = [&](int cc) {
        const float* xc = x + (size_t)cc * XCH;
        #pragma unroll
        for (int i = 0; i < 8; ++i) {
            const float* xb = xc + (size_t)(b0 + i) * (C_IN * XCH);
            #pragma unroll
            for (int s = 0; s < 4; ++s)
                gload_lds4(xb + rowsrc[s] + t, &xlds[b0 + i][s][0]);
        }
    };

    // prologue
    stage_w(0);
    stage_x(0);
    asm volatile("s_waitcnt vmcnt(0)" ::: "memory");
    __builtin_amdgcn_s_barrier();

    for (int c = 0; c < C_IN; ++c) {
        // outstanding here: x(c) [issued mid-compute of c-1] then w(c+1).
        // vmcnt(9) keeps only w(c+1) in flight => x(c) and w(c) complete.
        if (c + 1 < C_IN) {
            stage_w(c + 1);
            asm volatile("s_waitcnt vmcnt(9)" ::: "memory");
        } else {
            asm volatile("s_waitcnt vmcnt(0)" ::: "memory");
        }
        __builtin_amdgcn_s_barrier();

        const float* wb = wlds[c & 1];

        #pragma unroll
        for (int dh = 0; dh < 3; ++dh) {
            float2 wv[3][2];
            #pragma unroll
            for (int dw = 0; dw < 3; ++dw) {
                const int j = dh * 3 + dw;
                wv[dw][0] = *(const float2*)(wb + (j * 2 + 0) * 128 + pl);
                wv[dw][1] = *(const float2*)(wb + (j * 2 + 1) * 128 + pl);
            }

            // x tap-row from LDS: slot = rb+dh; halo via DPP (R10 pattern)
            float xs[8][4];
            #pragma unroll
            for (int i = 0; i < 8; ++i) {
                const float* xr_ = &xlds[b0 + i][0][0] + (rb + dh) * 64 + c0;
                float2 v = *(const float2*)xr_;
                v.x *= rvm[dh];
                v.y *= rvm[dh];
                const float xl = dpp_shr1(v.y);   // lane t-1's v.y (col c0-1)
                const float xr = dpp_shl1(v.x);   // lane t+1's v.x (col c0+2)
                xs[i][0] = lval ? xl : 0.f;
                xs[i][1] = v.x;
                xs[i][2] = v.y;
                xs[i][3] = rval ? xr : 0.f;
            }

            // after the LAST x ds_reads of this c: prefetch x(c+1) into the
            // (private) buffer. lgkmcnt(0) makes read-before-overwrite exact.
            if (dh == 2 && c + 1 < C_IN) {
                asm volatile("s_waitcnt lgkmcnt(0)" ::: "memory");
                stage_x(c + 1);
            }

            #pragma unroll
            for (int i = 0; i < 8; ++i)
                #pragma unroll
                for (int dw = 0; dw < 3; ++dw) {
                    acc[i][0].x = fmaf(xs[i][dw],     wv[dw][0].x, acc[i][0].x);
                    acc[i][0].y = fmaf(xs[i][dw + 1], wv[dw][0].y, acc[i][0].y);
                    acc[i][1].x = fmaf(xs[i][dw],     wv[dw][1].x, acc[i][1].x);
                    acc[i][1].y = fmaf(xs[i][dw + 1], wv[dw][1].y, acc[i][1].y);
                }
        }
        __builtin_amdgcn_s_barrier();   // wlds[c&1] reads done before overwrite
    }

    #pragma unroll
    for (int j = 0; j < 2; ++j) {
        const float2 bv = *(const float2*)(bias + (size_t)(o0 + j) * L_SZ + p);
        #pragma unroll
        for (int i = 0; i < 8; ++i) {
            float2 r;
            r.x = acc[i][j].x + bv.x;
            r.y = acc[i][j].y + bv.y;
            *(float2*)(out + ((size_t)(b0 + i) * C_OUT + (o0 + j)) * L_SZ + p) = r;
        }
    }
}

extern "C" void kernel_launch(void* const* d_in, const int* in_sizes, int n_in,
                              void* d_out, int out_size, void* d_ws, size_t ws_size,
                              hipStream_t stream) {
    const float* x    = (const float*)d_in[0];
    const float* wgt  = (const float*)d_in[1];
    const float* bias = (const float*)d_in[2];
    float* out        = (float*)d_out;

    dim3 block(64, 4);                    // 4 waves = 4 b-chunks of 8
    dim3 grid(H_SZ / 2, C_OUT / 2);       // 1024 blocks = 3/CU resident

    hipLaunchKernelGGL(rrf2d_kernel, grid, block, 0, stream, x, wgt, bias, out);
}